// Round 3
// baseline (273.649 us; speedup 1.0000x reference)
//
#include <hip/hip_runtime.h>
#include <hip/hip_bf16.h>

// MultiHeadAttention: B=2, S=2048, D=1024, H=16, DH=64, causal, eval-mode.
// Inputs/outputs are FLOAT32 (per reference); internal compute uses bf16 MFMA.
// Pipeline: cvt x -> bf16; transpose W (f32->bf16); fused QKV GEMM;
//           flash attention; out GEMM (stores f32 to d_out).

typedef short bf16x8 __attribute__((ext_vector_type(8)));   // 8 bf16 (4 VGPRs)
typedef float f32x4  __attribute__((ext_vector_type(4)));   // MFMA acc
typedef short s16x4  __attribute__((ext_vector_type(4)));

#define BB 2
#define SS 2048
#define DD 1024
#define HH 16
#define DHH 64

__device__ __forceinline__ unsigned short f2bf(float f) {
    unsigned u = __builtin_bit_cast(unsigned, f);
    u += 0x7FFFu + ((u >> 16) & 1u);      // round-to-nearest-even
    return (unsigned short)(u >> 16);
}
__device__ __forceinline__ float bf2f(unsigned short h) {
    unsigned u = ((unsigned)h) << 16;
    return __builtin_bit_cast(float, u);
}

// ---------------------------------------------------------------- f32 -> bf16
__global__ __launch_bounds__(256) void cvt_bf16(
    const float* __restrict__ src, unsigned short* __restrict__ dst, int n) {
    int i = (blockIdx.x * 256 + threadIdx.x) * 4;
    if (i >= n) return;
    float4 v = *reinterpret_cast<const float4*>(src + i);
    s16x4 p;
    p[0] = (short)f2bf(v.x); p[1] = (short)f2bf(v.y);
    p[2] = (short)f2bf(v.z); p[3] = (short)f2bf(v.w);
    *reinterpret_cast<s16x4*>(dst + i) = p;
}

// ---------------------------------------------------------------- transpose
// W[k][n] (1024x1024 f32) -> Wt[n][k] bf16.  blockIdx.z selects the matrix.
__global__ __launch_bounds__(256) void transpose_w(
    const float* __restrict__ w0, const float* __restrict__ w1,
    const float* __restrict__ w2, const float* __restrict__ w3,
    unsigned short* __restrict__ dst) {
    __shared__ float tile[64][65];
    const float* src = blockIdx.z == 0 ? w0 : blockIdx.z == 1 ? w1
                     : blockIdx.z == 2 ? w2 : w3;
    unsigned short* out = dst + (size_t)blockIdx.z * (DD * DD);
    int bx = blockIdx.x * 64, by = blockIdx.y * 64;
    int tx = threadIdx.x, ty = threadIdx.y;          // block (64,4)
    #pragma unroll
    for (int i = 0; i < 64; i += 4)
        tile[ty + i][tx] = src[(size_t)(by + ty + i) * DD + bx + tx];
    __syncthreads();
    #pragma unroll
    for (int i = 0; i < 64; i += 4)
        out[(size_t)(bx + ty + i) * DD + by + tx] = f2bf(tile[tx][ty + i]);
}

// ---------------------------------------------------------------- GEMM
// C[M x N] = A[M x 1024] @ Wt[N x 1024]^T (+bias).  128x128 tile, BK=64,
// 4 waves (2x2), each wave 64x64 = 4x4 mfma_16x16x32_bf16 tiles.
// mode 0: final projection, store C[m][1024] as FLOAT to d0f (+b0).
// mode 1: fused QKV (N=3072): sel=n>>10 -> Q(scaled)/K -> [b][h][s][d] bf16,
//         V -> [b][h][d][s] bf16 (transposed for the PV MFMA B-fragment).
__global__ __launch_bounds__(256) void gemm_proj(
    const unsigned short* __restrict__ A, const unsigned short* __restrict__ Wt,
    const float* __restrict__ b0, const float* __restrict__ b1,
    const float* __restrict__ b2,
    unsigned short* __restrict__ d0, unsigned short* __restrict__ d1,
    unsigned short* __restrict__ d2, float* __restrict__ d0f, int mode) {
    // +8 pad on the 64-elem K dim -> stride 72 elems (144B): conflict-free b128
    __shared__ __align__(16) unsigned short As[128 * 72];
    __shared__ __align__(16) unsigned short Bs[128 * 72];

    const int tid  = threadIdx.x;
    const int lane = tid & 63;
    const int w    = tid >> 6;
    const int col  = lane & 15;          // MFMA n / m fragment index
    const int quad = lane >> 4;
    const int wm   = (w >> 1) * 64;      // wave tile origin in M
    const int wn   = (w & 1) * 64;       // wave tile origin in N
    const int mb   = blockIdx.y * 128;
    const int nb   = blockIdx.x * 128;

    f32x4 acc[4][4];
    #pragma unroll
    for (int i = 0; i < 4; i++)
        #pragma unroll
        for (int j = 0; j < 4; j++) acc[i][j] = (f32x4){0.f, 0.f, 0.f, 0.f};

    const int srow = tid >> 3;           // staging: 32 rows per pass, 4 passes
    const int sc8  = (tid & 7) * 8;

    for (int kt = 0; kt < 1024; kt += 64) {
        __syncthreads();                 // WAR: prior frag reads done
        #pragma unroll
        for (int it = 0; it < 4; it++) {
            int row = srow + it * 32;
            bf16x8 av = *reinterpret_cast<const bf16x8*>(A  + (size_t)(mb + row) * 1024 + kt + sc8);
            bf16x8 bv = *reinterpret_cast<const bf16x8*>(Wt + (size_t)(nb + row) * 1024 + kt + sc8);
            *reinterpret_cast<bf16x8*>(As + row * 72 + sc8) = av;
            *reinterpret_cast<bf16x8*>(Bs + row * 72 + sc8) = bv;
        }
        __syncthreads();
        #pragma unroll
        for (int kk = 0; kk < 64; kk += 32) {
            bf16x8 af[4], bfr[4];
            #pragma unroll
            for (int i = 0; i < 4; i++)
                af[i] = *reinterpret_cast<const bf16x8*>(As + (wm + i * 16 + col) * 72 + kk + quad * 8);
            #pragma unroll
            for (int j = 0; j < 4; j++)
                bfr[j] = *reinterpret_cast<const bf16x8*>(Bs + (wn + j * 16 + col) * 72 + kk + quad * 8);
            #pragma unroll
            for (int i = 0; i < 4; i++)
                #pragma unroll
                for (int j = 0; j < 4; j++)
                    acc[i][j] = __builtin_amdgcn_mfma_f32_16x16x32_bf16(af[i], bfr[j], acc[i][j], 0, 0, 0);
        }
    }

    const float QSCALE = 0.125f * 1.44269504f;   // 1/sqrt(DH) * log2(e)
    #pragma unroll
    for (int i = 0; i < 4; i++) {
        int mg = mb + wm + i * 16 + quad * 4;    // C row = quad*4+reg
        #pragma unroll
        for (int j = 0; j < 4; j++) {
            int ng = nb + wn + j * 16 + col;     // C col = lane&15
            if (mode == 0) {
                float bbv = b0[ng];
                #pragma unroll
                for (int r = 0; r < 4; r++)
                    d0f[(size_t)(mg + r) * 1024 + ng] = acc[i][j][r] + bbv;
            } else {
                int sel = ng >> 10, n2 = ng & 1023;
                int h = n2 >> 6, dd2 = n2 & 63;
                int b = mg >> 11, s = mg & 2047;
                int bh = b * HH + h;
                const float* bp = sel == 0 ? b0 : sel == 1 ? b1 : b2;
                float bbv = bp[n2];
                if (sel == 0) {          // Q, pre-scaled for exp2-domain softmax
                    #pragma unroll
                    for (int r = 0; r < 4; r++)
                        d0[((size_t)bh * SS + s + r) * DHH + dd2] = f2bf((acc[i][j][r] + bbv) * QSCALE);
                } else if (sel == 1) {   // K
                    #pragma unroll
                    for (int r = 0; r < 4; r++)
                        d1[((size_t)bh * SS + s + r) * DHH + dd2] = f2bf(acc[i][j][r] + bbv);
                } else {                 // V^T: [b][h][d][s]; 4 consecutive s -> 8B store
                    s16x4 pack;
                    #pragma unroll
                    for (int r = 0; r < 4; r++) pack[r] = (short)f2bf(acc[i][j][r] + bbv);
                    *reinterpret_cast<s16x4*>(d2 + ((size_t)bh * DHH + dd2) * SS + s) = pack;
                }
            }
        }
    }
}

// ---------------------------------------------------------------- attention
// Block = 4 waves, 64 q-rows (16/wave).  Key tiles of 64 staged in LDS.
// Online softmax per q-row; stats replicated across the 16 lanes of a quad.
__global__ __launch_bounds__(256) void attn(
    const unsigned short* __restrict__ Q, const unsigned short* __restrict__ K,
    const unsigned short* __restrict__ Vt, unsigned short* __restrict__ O) {
    __shared__ __align__(16) unsigned short Ks[64 * 72];   // [key][dh] pad 72
    __shared__ __align__(16) unsigned short Vs[64 * 72];   // [dh][key] pad 72
    __shared__ __align__(16) unsigned short Ps[4][16 * 40]; // per-wave P [m][k] pad 40

    const int tid  = threadIdx.x;
    const int lane = tid & 63;
    const int w    = tid >> 6;
    const int col  = lane & 15;
    const int quad = lane >> 4;
    const int bh   = blockIdx.x & 31;                 // b*16+h
    const int qt   = 31 - (blockIdx.x >> 5);          // heavy (late) q-tiles first
    const int qb   = qt * 64;
    const int qrow = qb + w * 16 + col;               // A-frag m = lane&15

    const size_t qbase = ((size_t)bh * SS + qrow) * DHH;
    bf16x8 qlo = *reinterpret_cast<const bf16x8*>(Q + qbase + quad * 8);
    bf16x8 qhi = *reinterpret_cast<const bf16x8*>(Q + qbase + 32 + quad * 8);

    f32x4 o[4];
    #pragma unroll
    for (int d = 0; d < 4; d++) o[d] = (f32x4){0.f, 0.f, 0.f, 0.f};
    float m_i[4], l_i[4];
    #pragma unroll
    for (int r = 0; r < 4; r++) { m_i[r] = -1e30f; l_i[r] = 0.f; }

    const int srow = tid >> 3;
    const int sc8  = (tid & 7) * 8;

    for (int kt = 0; kt <= qt; kt++) {
        __syncthreads();
        #pragma unroll
        for (int it = 0; it < 2; it++) {   // stage K (8KB) + V^T (8KB)
            int row = srow + it * 32;
            bf16x8 kv = *reinterpret_cast<const bf16x8*>(K  + ((size_t)bh * SS + kt * 64 + row) * DHH + sc8);
            bf16x8 vv = *reinterpret_cast<const bf16x8*>(Vt + ((size_t)bh * DHH + row) * SS + kt * 64 + sc8);
            *reinterpret_cast<bf16x8*>(Ks + row * 72 + sc8) = kv;
            *reinterpret_cast<bf16x8*>(Vs + row * 72 + sc8) = vv;
        }
        __syncthreads();
        const bool diag = (kt == qt);      // only the diagonal tile needs masking

        #pragma unroll
        for (int c2 = 0; c2 < 2; c2++) {   // 32 keys per chunk
            f32x4 sc[2];
            #pragma unroll
            for (int ct = 0; ct < 2; ct++) {
                int key = c2 * 32 + ct * 16 + col;        // B-frag n = lane&15
                bf16x8 klo = *reinterpret_cast<const bf16x8*>(Ks + key * 72 + quad * 8);
                bf16x8 khi = *reinterpret_cast<const bf16x8*>(Ks + key * 72 + 32 + quad * 8);
                f32x4 z = (f32x4){0.f, 0.f, 0.f, 0.f};
                z = __builtin_amdgcn_mfma_f32_16x16x32_bf16(qlo, klo, z, 0, 0, 0);
                z = __builtin_amdgcn_mfma_f32_16x16x32_bf16(qhi, khi, z, 0, 0, 0);
                sc[ct] = z;
            }
            if (diag) {
                #pragma unroll
                for (int ct = 0; ct < 2; ct++) {
                    int kg = kt * 64 + c2 * 32 + ct * 16 + col;
                    #pragma unroll
                    for (int r = 0; r < 4; r++) {
                        int qg = qb + w * 16 + quad * 4 + r;   // C row
                        if (kg > qg) sc[ct][r] = -3.0e38f;
                    }
                }
            }
            float mnew[4], alpha[4];
            #pragma unroll
            for (int r = 0; r < 4; r++) {
                float t = fmaxf(sc[0][r], sc[1][r]);
                t = fmaxf(t, __shfl_xor(t, 1));
                t = fmaxf(t, __shfl_xor(t, 2));
                t = fmaxf(t, __shfl_xor(t, 4));
                t = fmaxf(t, __shfl_xor(t, 8));
                mnew[r]  = fmaxf(m_i[r], t);
                alpha[r] = exp2f(m_i[r] - mnew[r]);
                m_i[r]   = mnew[r];
            }
            unsigned short p0[4], p1[4];
            #pragma unroll
            for (int r = 0; r < 4; r++) {
                p0[r] = f2bf(exp2f(sc[0][r] - mnew[r]));
                p1[r] = f2bf(exp2f(sc[1][r] - mnew[r]));
                float t = bf2f(p0[r]) + bf2f(p1[r]);   // sum the *rounded* P
                t += __shfl_xor(t, 1);
                t += __shfl_xor(t, 2);
                t += __shfl_xor(t, 4);
                t += __shfl_xor(t, 8);
                l_i[r] = l_i[r] * alpha[r] + t;
            }
            unsigned short* pw = Ps[w];                // C-layout -> A-layout via LDS
            #pragma unroll
            for (int r = 0; r < 4; r++) {
                pw[(quad * 4 + r) * 40 + col]      = p0[r];
                pw[(quad * 4 + r) * 40 + 16 + col] = p1[r];
            }
            #pragma unroll
            for (int d = 0; d < 4; d++)
                #pragma unroll
                for (int r = 0; r < 4; r++) o[d][r] *= alpha[r];
            bf16x8 pf = *reinterpret_cast<const bf16x8*>(pw + (lane & 15) * 40 + quad * 8);
            #pragma unroll
            for (int d = 0; d < 4; d++) {
                bf16x8 vf = *reinterpret_cast<const bf16x8*>(Vs + (d * 16 + col) * 72 + c2 * 32 + quad * 8);
                o[d] = __builtin_amdgcn_mfma_f32_16x16x32_bf16(pf, vf, o[d], 0, 0, 0);
            }
        }
    }
    // epilogue: O[b][s][h*64+d] bf16, normalized by l
    #pragma unroll
    for (int r = 0; r < 4; r++) {
        int sq = qb + w * 16 + quad * 4 + r;
        float inv = 1.0f / l_i[r];
        size_t base = ((size_t)(bh >> 4) * SS + sq) * DD + (size_t)(bh & 15) * DHH;
        #pragma unroll
        for (int d = 0; d < 4; d++)
            O[base + d * 16 + col] = f2bf(o[d][r] * inv);
    }
}

// ---------------------------------------------------------------- launch
extern "C" void kernel_launch(void* const* d_in, const int* in_sizes, int n_in,
                              void* d_out, int out_size, void* d_ws, size_t ws_size,
                              hipStream_t stream) {
    (void)in_sizes; (void)n_in; (void)out_size; (void)ws_size;
    const float* x  = (const float*)d_in[0];
    // d_in[1] = mask (int32) — causal mask computed analytically
    const float* Wq = (const float*)d_in[2];
    const float* bq = (const float*)d_in[3];
    const float* Wk = (const float*)d_in[4];
    const float* bk = (const float*)d_in[5];
    const float* Wv = (const float*)d_in[6];
    const float* bv = (const float*)d_in[7];
    const float* Wo = (const float*)d_in[8];
    const float* bo = (const float*)d_in[9];
    float* out = (float*)d_out;

    // Workspace layout (40 MB):
    //  0- 8 MB : x_bf (bf16), later reused for O (attn output, bf16)
    //  8-16 MB : Q [b][h][s][d] bf16 (pre-scaled)
    // 16-24 MB : K [b][h][s][d] bf16
    // 24-32 MB : V^T [b][h][d][s] bf16
    // 32-40 MB : Wt[4][1024][1024] bf16 (Wq^T, Wk^T, Wv^T, Wo^T)
    char* ws = (char*)d_ws;
    unsigned short* xbf = (unsigned short*)(ws);
    unsigned short* qws = (unsigned short*)(ws + ((size_t)8  << 20));
    unsigned short* kws = (unsigned short*)(ws + ((size_t)16 << 20));
    unsigned short* vws = (unsigned short*)(ws + ((size_t)24 << 20));
    unsigned short* wt  = (unsigned short*)(ws + ((size_t)32 << 20));
    unsigned short* ows = xbf;   // O overwrites x_bf (dead after QKV GEMM)

    const int nx = BB * SS * DD;               // 4,194,304
    cvt_bf16<<<dim3(nx / 1024), 256, 0, stream>>>(x, xbf, nx);
    transpose_w<<<dim3(16, 16, 4), dim3(64, 4), 0, stream>>>(Wq, Wk, Wv, Wo, wt);
    gemm_proj<<<dim3(24, 32), 256, 0, stream>>>(xbf, wt, bq, bk, bv,
                                                qws, kws, vws, nullptr, 1);
    attn<<<dim3(1024), 256, 0, stream>>>(qws, kws, vws, ows);
    gemm_proj<<<dim3(8, 32), 256, 0, stream>>>(ows, wt + (size_t)3 * 1024 * 1024,
                                               bo, nullptr, nullptr,
                                               nullptr, nullptr, nullptr, out, 0);
}

// Round 4
// 244.563 us; speedup vs baseline: 1.1189x; 1.1189x over previous
//
#include <hip/hip_runtime.h>
#include <hip/hip_bf16.h>

// MultiHeadAttention: B=2, S=2048, D=1024, H=16, DH=64, causal, eval-mode.
// f32 I/O, bf16 MFMA internally.
// R4: GEMM staging via global_load_lds(16B) + XOR-swizzled LDS (stride 64);
//     attn: per-64-key softmax, row-sums via ones-fragment MFMA (l = 5th acc
//     column), 512 balanced blocks (q-tile pairs p & 31-p).

typedef short bf16x8 __attribute__((ext_vector_type(8)));
typedef float f32x4  __attribute__((ext_vector_type(4)));
typedef short s16x4  __attribute__((ext_vector_type(4)));

#define BB 2
#define SS 2048
#define DD 1024
#define HH 16
#define DHH 64

__device__ __forceinline__ unsigned short f2bf(float f) {
    unsigned u = __builtin_bit_cast(unsigned, f);
    u += 0x7FFFu + ((u >> 16) & 1u);      // RNE
    return (unsigned short)(u >> 16);
}
__device__ __forceinline__ float bf2f(unsigned short h) {
    unsigned u = ((unsigned)h) << 16;
    return __builtin_bit_cast(float, u);
}
// async 16B global -> LDS (dest = wave-uniform base + lane*16B)
__device__ __forceinline__ void cp16(const unsigned short* g, unsigned short* l) {
    __builtin_amdgcn_global_load_lds(
        (const __attribute__((address_space(1))) unsigned int*)(g),
        (__attribute__((address_space(3))) unsigned int*)(l), 16, 0, 0);
}

// ---------------------------------------------------------------- f32 -> bf16
__global__ __launch_bounds__(256) void cvt_bf16(
    const float* __restrict__ src, unsigned short* __restrict__ dst, int n) {
    int i = (blockIdx.x * 256 + threadIdx.x) * 4;
    if (i >= n) return;
    float4 v = *reinterpret_cast<const float4*>(src + i);
    s16x4 p;
    p[0] = (short)f2bf(v.x); p[1] = (short)f2bf(v.y);
    p[2] = (short)f2bf(v.z); p[3] = (short)f2bf(v.w);
    *reinterpret_cast<s16x4*>(dst + i) = p;
}

// ---------------------------------------------------------------- transpose
__global__ __launch_bounds__(256) void transpose_w(
    const float* __restrict__ w0, const float* __restrict__ w1,
    const float* __restrict__ w2, const float* __restrict__ w3,
    unsigned short* __restrict__ dst) {
    __shared__ float tile[64][65];
    const float* src = blockIdx.z == 0 ? w0 : blockIdx.z == 1 ? w1
                     : blockIdx.z == 2 ? w2 : w3;
    unsigned short* out = dst + (size_t)blockIdx.z * (DD * DD);
    int bx = blockIdx.x * 64, by = blockIdx.y * 64;
    int tx = threadIdx.x, ty = threadIdx.y;          // block (64,4)
    #pragma unroll
    for (int i = 0; i < 64; i += 4)
        tile[ty + i][tx] = src[(size_t)(by + ty + i) * DD + bx + tx];
    __syncthreads();
    #pragma unroll
    for (int i = 0; i < 64; i += 4)
        out[(size_t)(bx + ty + i) * DD + by + tx] = f2bf(tile[tx][ty + i]);
}

// ---------------------------------------------------------------- GEMM
// C[Mx N] = A[Mx1024] @ Wt[Nx1024]^T (+bias). 128x128 tile, BK=64, 4 waves.
// LDS stride 64 (unpadded), k-groups XOR-swizzled by row&7: staging uses
// global_load_lds 16B with source-side swizzle; frag reads land conflict-free.
__global__ __launch_bounds__(256) void gemm_proj(
    const unsigned short* __restrict__ A, const unsigned short* __restrict__ Wt,
    const float* __restrict__ b0, const float* __restrict__ b1,
    const float* __restrict__ b2,
    unsigned short* __restrict__ d0, unsigned short* __restrict__ d1,
    unsigned short* __restrict__ d2, float* __restrict__ d0f, int mode) {
    __shared__ __align__(16) unsigned short As[128 * 64];
    __shared__ __align__(16) unsigned short Bs[128 * 64];

    const int tid  = threadIdx.x;
    const int lane = tid & 63;
    const int w    = tid >> 6;
    const int col  = lane & 15;
    const int quad = lane >> 4;
    const int wm   = (w >> 1) * 64;
    const int wn   = (w & 1) * 64;
    const int mb   = blockIdx.y * 128;
    const int nb   = blockIdx.x * 128;

    const int r8 = lane >> 3, gg = lane & 7;
    const int srcoff = ((gg ^ r8) * 8);          // source k-group swizzle
    const int cswz = col & 7;                    // frag-read unswizzle key

    f32x4 acc[4][4];
    #pragma unroll
    for (int i = 0; i < 4; i++)
        #pragma unroll
        for (int j = 0; j < 4; j++) acc[i][j] = (f32x4){0.f, 0.f, 0.f, 0.f};

    for (int kt = 0; kt < 1024; kt += 64) {
        __syncthreads();                 // WAR: prior frag reads done
        #pragma unroll
        for (int it = 0; it < 4; it++) {
            int row = w * 32 + it * 8 + r8;      // row&7 == r8
            cp16(A  + (size_t)(mb + row) * 1024 + kt + srcoff, As + (w * 32 + it * 8) * 64);
            cp16(Wt + (size_t)(nb + row) * 1024 + kt + srcoff, Bs + (w * 32 + it * 8) * 64);
        }
        __syncthreads();                 // drains vmcnt: LDS ready
        #pragma unroll
        for (int kk = 0; kk < 64; kk += 32) {
            const int kg = (kk >> 3) + quad;     // 0..7
            const int pos = ((kg ^ cswz) * 8);
            bf16x8 af[4], bfr[4];
            #pragma unroll
            for (int i = 0; i < 4; i++)
                af[i] = *reinterpret_cast<const bf16x8*>(As + (wm + i * 16 + col) * 64 + pos);
            #pragma unroll
            for (int j = 0; j < 4; j++)
                bfr[j] = *reinterpret_cast<const bf16x8*>(Bs + (wn + j * 16 + col) * 64 + pos);
            #pragma unroll
            for (int i = 0; i < 4; i++)
                #pragma unroll
                for (int j = 0; j < 4; j++)
                    acc[i][j] = __builtin_amdgcn_mfma_f32_16x16x32_bf16(af[i], bfr[j], acc[i][j], 0, 0, 0);
        }
    }

    const float QSCALE = 0.125f * 1.44269504f;   // 1/sqrt(DH) * log2(e)
    #pragma unroll
    for (int i = 0; i < 4; i++) {
        int mg = mb + wm + i * 16 + quad * 4;    // C row = quad*4+reg
        #pragma unroll
        for (int j = 0; j < 4; j++) {
            int ng = nb + wn + j * 16 + col;     // C col = lane&15
            if (mode == 0) {
                float bbv = b0[ng];
                #pragma unroll
                for (int r = 0; r < 4; r++)
                    d0f[(size_t)(mg + r) * 1024 + ng] = acc[i][j][r] + bbv;
            } else {
                int sel = ng >> 10, n2 = ng & 1023;
                int h = n2 >> 6, dd2 = n2 & 63;
                int b = mg >> 11, s = mg & 2047;
                int bh = b * HH + h;
                const float* bp = sel == 0 ? b0 : sel == 1 ? b1 : b2;
                float bbv = bp[n2];
                if (sel == 0) {          // Q (pre-scaled for exp2 softmax)
                    #pragma unroll
                    for (int r = 0; r < 4; r++)
                        d0[((size_t)bh * SS + s + r) * DHH + dd2] = f2bf((acc[i][j][r] + bbv) * QSCALE);
                } else if (sel == 1) {   // K
                    #pragma unroll
                    for (int r = 0; r < 4; r++)
                        d1[((size_t)bh * SS + s + r) * DHH + dd2] = f2bf(acc[i][j][r] + bbv);
                } else {                 // V^T [b][h][d][s]
                    s16x4 pack;
                    #pragma unroll
                    for (int r = 0; r < 4; r++) pack[r] = (short)f2bf(acc[i][j][r] + bbv);
                    *reinterpret_cast<s16x4*>(d2 + ((size_t)bh * DHH + dd2) * SS + s) = pack;
                }
            }
        }
    }
}

// ---------------------------------------------------------------- attention
// 512 blocks: bh = bx&31, pair p = bx>>5; block does q-tiles p and 31-p
// (balanced 33 key-tiles each). 4 waves x 16 q-rows. Softmax update once per
// 64-key tile; row sums via constant ones-fragment MFMA into o[4] (= l).
__global__ __launch_bounds__(256) void attn(
    const unsigned short* __restrict__ Q, const unsigned short* __restrict__ K,
    const unsigned short* __restrict__ Vt, unsigned short* __restrict__ O) {
    __shared__ __align__(16) unsigned short Ks[64 * 64];   // [key][dh] swizzled
    __shared__ __align__(16) unsigned short Vs[64 * 64];   // [dh][key] swizzled
    __shared__ __align__(16) unsigned short Ps[4][16 * 72]; // per-wave P [m][k] pad

    const int tid  = threadIdx.x;
    const int lane = tid & 63;
    const int w    = tid >> 6;
    const int col  = lane & 15;
    const int quad = lane >> 4;
    const int bh   = blockIdx.x & 31;
    const int p    = blockIdx.x >> 5;          // 0..15
    const int r8 = lane >> 3, gg = lane & 7;
    const int srcoff = ((gg ^ r8) * 8);
    const int cswz = col & 7;

    bf16x8 onesf;                               // B-frag: col 64 of V == 1
    #pragma unroll
    for (int j = 0; j < 8; j++) onesf[j] = (col == 0) ? (short)0x3F80 : (short)0;

    for (int half = 0; half < 2; half++) {
        const int qt = half ? (31 - p) : p;
        const int qb = qt * 64;
        const int qrow = qb + w * 16 + col;
        const size_t qbase = ((size_t)bh * SS + qrow) * DHH;
        bf16x8 qlo = *reinterpret_cast<const bf16x8*>(Q + qbase + quad * 8);
        bf16x8 qhi = *reinterpret_cast<const bf16x8*>(Q + qbase + 32 + quad * 8);

        f32x4 o[5];
        #pragma unroll
        for (int d = 0; d < 5; d++) o[d] = (f32x4){0.f, 0.f, 0.f, 0.f};
        float m_i[4];
        #pragma unroll
        for (int r = 0; r < 4; r++) m_i[r] = -1e30f;

        for (int kt = 0; kt <= qt; kt++) {
            __syncthreads();
            #pragma unroll
            for (int it = 0; it < 2; it++) {     // stage K + V^T (8KB each)
                int row = w * 16 + it * 8 + r8;  // row&7 == r8
                cp16(K  + ((size_t)bh * SS + kt * 64 + row) * DHH + srcoff,
                     Ks + (w * 16 + it * 8) * 64);
                cp16(Vt + ((size_t)bh * DHH + row) * SS + kt * 64 + srcoff,
                     Vs + (w * 16 + it * 8) * 64);
            }
            __syncthreads();

            // ---- scores for 64 keys (16 rows x 64 keys per wave)
            f32x4 sc[4];
            #pragma unroll
            for (int nt = 0; nt < 4; nt++) {
                int key = nt * 16 + col;
                int ks = cswz ^ 0;   // silence unused warn pattern
                (void)ks;
                bf16x8 klo = *reinterpret_cast<const bf16x8*>(Ks + key * 64 + ((quad       ^ cswz) * 8));
                bf16x8 khi = *reinterpret_cast<const bf16x8*>(Ks + key * 64 + (((4 + quad) ^ cswz) * 8));
                f32x4 z = (f32x4){0.f, 0.f, 0.f, 0.f};
                z = __builtin_amdgcn_mfma_f32_16x16x32_bf16(qlo, klo, z, 0, 0, 0);
                z = __builtin_amdgcn_mfma_f32_16x16x32_bf16(qhi, khi, z, 0, 0, 0);
                sc[nt] = z;
            }
            if (kt == qt) {                      // causal mask, diagonal tile only
                #pragma unroll
                for (int nt = 0; nt < 4; nt++) {
                    int kg = kt * 64 + nt * 16 + col;
                    #pragma unroll
                    for (int r = 0; r < 4; r++) {
                        int qg = qb + w * 16 + quad * 4 + r;
                        if (kg > qg) sc[nt][r] = -3.0e38f;
                    }
                }
            }
            // ---- one online-softmax update per 64 keys
            float mnew[4], alpha[4];
            #pragma unroll
            for (int r = 0; r < 4; r++) {
                float t = fmaxf(fmaxf(sc[0][r], sc[1][r]), fmaxf(sc[2][r], sc[3][r]));
                t = fmaxf(t, __shfl_xor(t, 1));
                t = fmaxf(t, __shfl_xor(t, 2));
                t = fmaxf(t, __shfl_xor(t, 4));
                t = fmaxf(t, __shfl_xor(t, 8));
                mnew[r]  = fmaxf(m_i[r], t);
                alpha[r] = exp2f(m_i[r] - mnew[r]);
                m_i[r]   = mnew[r];
            }
            unsigned short* pw = Ps[w];          // C-layout -> A-layout
            #pragma unroll
            for (int nt = 0; nt < 4; nt++)
                #pragma unroll
                for (int r = 0; r < 4; r++)
                    pw[(quad * 4 + r) * 72 + nt * 16 + col] = f2bf(exp2f(sc[nt][r] - mnew[r]));
            #pragma unroll
            for (int d = 0; d < 5; d++)
                #pragma unroll
                for (int r = 0; r < 4; r++) o[d][r] *= alpha[r];
            bf16x8 pf0 = *reinterpret_cast<const bf16x8*>(pw + col * 72 + quad * 8);
            bf16x8 pf1 = *reinterpret_cast<const bf16x8*>(pw + col * 72 + 32 + quad * 8);
            #pragma unroll
            for (int dt = 0; dt < 4; dt++) {
                int rv = dt * 16 + col;          // Vs row (= output d index)
                bf16x8 vf0 = *reinterpret_cast<const bf16x8*>(Vs + rv * 64 + ((quad       ^ cswz) * 8));
                bf16x8 vf1 = *reinterpret_cast<const bf16x8*>(Vs + rv * 64 + (((4 + quad) ^ cswz) * 8));
                o[dt] = __builtin_amdgcn_mfma_f32_16x16x32_bf16(pf0, vf0, o[dt], 0, 0, 0);
                o[dt] = __builtin_amdgcn_mfma_f32_16x16x32_bf16(pf1, vf1, o[dt], 0, 0, 0);
            }
            o[4] = __builtin_amdgcn_mfma_f32_16x16x32_bf16(pf0, onesf, o[4], 0, 0, 0);
            o[4] = __builtin_amdgcn_mfma_f32_16x16x32_bf16(pf1, onesf, o[4], 0, 0, 0);
        }

        // epilogue: l lives in o[4][r] of lanes col==0; broadcast within quad
        #pragma unroll
        for (int r = 0; r < 4; r++) {
            float lv = __shfl(o[4][r], lane & 48);
            float inv = 1.0f / lv;
            int sq = qb + w * 16 + quad * 4 + r;
            size_t base = ((size_t)(bh >> 4) * SS + sq) * DD + (size_t)(bh & 15) * DHH;
            #pragma unroll
            for (int dt = 0; dt < 4; dt++)
                O[base + dt * 16 + col] = f2bf(o[dt][r] * inv);
        }
    }
}

// ---------------------------------------------------------------- launch
extern "C" void kernel_launch(void* const* d_in, const int* in_sizes, int n_in,
                              void* d_out, int out_size, void* d_ws, size_t ws_size,
                              hipStream_t stream) {
    (void)in_sizes; (void)n_in; (void)out_size; (void)ws_size;
    const float* x  = (const float*)d_in[0];
    const float* Wq = (const float*)d_in[2];
    const float* bq = (const float*)d_in[3];
    const float* Wk = (const float*)d_in[4];
    const float* bk = (const float*)d_in[5];
    const float* Wv = (const float*)d_in[6];
    const float* bv = (const float*)d_in[7];
    const float* Wo = (const float*)d_in[8];
    const float* bo = (const float*)d_in[9];
    float* out = (float*)d_out;

    // ws (40 MB): x_bf/O | Q | K | V^T | Wt x4
    char* ws = (char*)d_ws;
    unsigned short* xbf = (unsigned short*)(ws);
    unsigned short* qws = (unsigned short*)(ws + ((size_t)8  << 20));
    unsigned short* kws = (unsigned short*)(ws + ((size_t)16 << 20));
    unsigned short* vws = (unsigned short*)(ws + ((size_t)24 << 20));
    unsigned short* wt  = (unsigned short*)(ws + ((size_t)32 << 20));
    unsigned short* ows = xbf;   // O overwrites x_bf (dead after QKV GEMM)

    const int nx = BB * SS * DD;               // 4,194,304
    cvt_bf16<<<dim3(nx / 1024), 256, 0, stream>>>(x, xbf, nx);
    transpose_w<<<dim3(16, 16, 4), dim3(64, 4), 0, stream>>>(Wq, Wk, Wv, Wo, wt);
    gemm_proj<<<dim3(24, 32), 256, 0, stream>>>(xbf, wt, bq, bk, bv,
                                                qws, kws, vws, nullptr, 1);
    attn<<<dim3(512), 256, 0, stream>>>(qws, kws, vws, ows);
    gemm_proj<<<dim3(8, 32), 256, 0, stream>>>(ows, wt + (size_t)3 * 1024 * 1024,
                                               bo, nullptr, nullptr,
                                               nullptr, nullptr, nullptr, out, 0);
}

// Round 5
// 222.206 us; speedup vs baseline: 1.2315x; 1.1006x over previous
//
#include <hip/hip_runtime.h>
#include <hip/hip_bf16.h>

// MultiHeadAttention: B=2, S=2048, D=1024, H=16, DH=64, causal, eval-mode.
// f32 I/O, bf16 MFMA internally.
// R5: attn grid back to 1024 (1 q-tile/block, heavy-first) + alpha-skip;
//     out-GEMM re-tiled 128x64 (512 blocks, 2/CU).

typedef short bf16x8 __attribute__((ext_vector_type(8)));
typedef float f32x4  __attribute__((ext_vector_type(4)));
typedef short s16x4  __attribute__((ext_vector_type(4)));

#define BB 2
#define SS 2048
#define DD 1024
#define HH 16
#define DHH 64

__device__ __forceinline__ unsigned short f2bf(float f) {
    unsigned u = __builtin_bit_cast(unsigned, f);
    u += 0x7FFFu + ((u >> 16) & 1u);      // RNE
    return (unsigned short)(u >> 16);
}
// async 16B global -> LDS (dest = wave-uniform base + lane*16B)
__device__ __forceinline__ void cp16(const unsigned short* g, unsigned short* l) {
    __builtin_amdgcn_global_load_lds(
        (const __attribute__((address_space(1))) unsigned int*)(g),
        (__attribute__((address_space(3))) unsigned int*)(l), 16, 0, 0);
}

// ---------------------------------------------------------------- f32 -> bf16
__global__ __launch_bounds__(256) void cvt_bf16(
    const float* __restrict__ src, unsigned short* __restrict__ dst, int n) {
    int i = (blockIdx.x * 256 + threadIdx.x) * 4;
    if (i >= n) return;
    float4 v = *reinterpret_cast<const float4*>(src + i);
    s16x4 p;
    p[0] = (short)f2bf(v.x); p[1] = (short)f2bf(v.y);
    p[2] = (short)f2bf(v.z); p[3] = (short)f2bf(v.w);
    *reinterpret_cast<s16x4*>(dst + i) = p;
}

// ---------------------------------------------------------------- transpose
__global__ __launch_bounds__(256) void transpose_w(
    const float* __restrict__ w0, const float* __restrict__ w1,
    const float* __restrict__ w2, const float* __restrict__ w3,
    unsigned short* __restrict__ dst) {
    __shared__ float tile[64][65];
    const float* src = blockIdx.z == 0 ? w0 : blockIdx.z == 1 ? w1
                     : blockIdx.z == 2 ? w2 : w3;
    unsigned short* out = dst + (size_t)blockIdx.z * (DD * DD);
    int bx = blockIdx.x * 64, by = blockIdx.y * 64;
    int tx = threadIdx.x, ty = threadIdx.y;          // block (64,4)
    #pragma unroll
    for (int i = 0; i < 64; i += 4)
        tile[ty + i][tx] = src[(size_t)(by + ty + i) * DD + bx + tx];
    __syncthreads();
    #pragma unroll
    for (int i = 0; i < 64; i += 4)
        out[(size_t)(bx + ty + i) * DD + by + tx] = f2bf(tile[tx][ty + i]);
}

// ---------------------------------------------------------------- QKV GEMM
// C[4096x3072] = A @ Wt^T (+bias). 128x128 tile, BK=64, 4 waves (2x2).
// LDS stride 64, k-groups XOR-swizzled by row&7; staging via cp16.
__global__ __launch_bounds__(256) void gemm_qkv(
    const unsigned short* __restrict__ A, const unsigned short* __restrict__ Wt,
    const float* __restrict__ b0, const float* __restrict__ b1,
    const float* __restrict__ b2,
    unsigned short* __restrict__ d0, unsigned short* __restrict__ d1,
    unsigned short* __restrict__ d2) {
    __shared__ __align__(16) unsigned short As[128 * 64];
    __shared__ __align__(16) unsigned short Bs[128 * 64];

    const int tid  = threadIdx.x;
    const int lane = tid & 63;
    const int w    = tid >> 6;
    const int col  = lane & 15;
    const int quad = lane >> 4;
    const int wm   = (w >> 1) * 64;
    const int wn   = (w & 1) * 64;
    const int mb   = blockIdx.y * 128;
    const int nb   = blockIdx.x * 128;

    const int r8 = lane >> 3, gg = lane & 7;
    const int srcoff = ((gg ^ r8) * 8);          // source k-group swizzle
    const int cswz = col & 7;                    // frag-read unswizzle key

    f32x4 acc[4][4];
    #pragma unroll
    for (int i = 0; i < 4; i++)
        #pragma unroll
        for (int j = 0; j < 4; j++) acc[i][j] = (f32x4){0.f, 0.f, 0.f, 0.f};

    for (int kt = 0; kt < 1024; kt += 64) {
        __syncthreads();
        #pragma unroll
        for (int it = 0; it < 4; it++) {
            int row = w * 32 + it * 8 + r8;      // row&7 == r8
            cp16(A  + (size_t)(mb + row) * 1024 + kt + srcoff, As + (w * 32 + it * 8) * 64);
            cp16(Wt + (size_t)(nb + row) * 1024 + kt + srcoff, Bs + (w * 32 + it * 8) * 64);
        }
        __syncthreads();
        #pragma unroll
        for (int kk = 0; kk < 64; kk += 32) {
            const int kg = (kk >> 3) + quad;
            const int pos = ((kg ^ cswz) * 8);
            bf16x8 af[4], bfr[4];
            #pragma unroll
            for (int i = 0; i < 4; i++)
                af[i] = *reinterpret_cast<const bf16x8*>(As + (wm + i * 16 + col) * 64 + pos);
            #pragma unroll
            for (int j = 0; j < 4; j++)
                bfr[j] = *reinterpret_cast<const bf16x8*>(Bs + (wn + j * 16 + col) * 64 + pos);
            #pragma unroll
            for (int i = 0; i < 4; i++)
                #pragma unroll
                for (int j = 0; j < 4; j++)
                    acc[i][j] = __builtin_amdgcn_mfma_f32_16x16x32_bf16(af[i], bfr[j], acc[i][j], 0, 0, 0);
        }
    }

    const float QSCALE = 0.125f * 1.44269504f;   // 1/sqrt(DH) * log2(e)
    #pragma unroll
    for (int i = 0; i < 4; i++) {
        int mg = mb + wm + i * 16 + quad * 4;    // C row = quad*4+reg
        #pragma unroll
        for (int j = 0; j < 4; j++) {
            int ng = nb + wn + j * 16 + col;     // C col = lane&15
            int sel = ng >> 10, n2 = ng & 1023;
            int h = n2 >> 6, dd2 = n2 & 63;
            int b = mg >> 11, s = mg & 2047;
            int bh = b * HH + h;
            const float* bp = sel == 0 ? b0 : sel == 1 ? b1 : b2;
            float bbv = bp[n2];
            if (sel == 0) {          // Q (pre-scaled for exp2 softmax)
                #pragma unroll
                for (int r = 0; r < 4; r++)
                    d0[((size_t)bh * SS + s + r) * DHH + dd2] = f2bf((acc[i][j][r] + bbv) * QSCALE);
            } else if (sel == 1) {   // K
                #pragma unroll
                for (int r = 0; r < 4; r++)
                    d1[((size_t)bh * SS + s + r) * DHH + dd2] = f2bf(acc[i][j][r] + bbv);
            } else {                 // V^T [b][h][d][s]
                s16x4 pack;
                #pragma unroll
                for (int r = 0; r < 4; r++) pack[r] = (short)f2bf(acc[i][j][r] + bbv);
                *reinterpret_cast<s16x4*>(d2 + ((size_t)bh * DHH + dd2) * SS + s) = pack;
            }
        }
    }
}

// ---------------------------------------------------------------- out GEMM
// C[4096x1024] = A @ Wt^T + b, f32 out. 128x64 tile, BK=64, 4 waves (2x2),
// wave tile 64x32 (acc 4x2). Grid (16,32)=512 blocks -> 2 blocks/CU.
__global__ __launch_bounds__(256) void gemm_out(
    const unsigned short* __restrict__ A, const unsigned short* __restrict__ Wt,
    const float* __restrict__ b0, float* __restrict__ d0f) {
    __shared__ __align__(16) unsigned short As[128 * 64];
    __shared__ __align__(16) unsigned short Bs[64 * 64];

    const int tid  = threadIdx.x;
    const int lane = tid & 63;
    const int w    = tid >> 6;
    const int col  = lane & 15;
    const int quad = lane >> 4;
    const int wm   = (w >> 1) * 64;
    const int wn   = (w & 1) * 32;
    const int mb   = blockIdx.y * 128;
    const int nb   = blockIdx.x * 64;

    const int r8 = lane >> 3, gg = lane & 7;
    const int srcoff = ((gg ^ r8) * 8);
    const int cswz = col & 7;

    f32x4 acc[4][2];
    #pragma unroll
    for (int i = 0; i < 4; i++)
        #pragma unroll
        for (int j = 0; j < 2; j++) acc[i][j] = (f32x4){0.f, 0.f, 0.f, 0.f};

    for (int kt = 0; kt < 1024; kt += 64) {
        __syncthreads();
        #pragma unroll
        for (int it = 0; it < 4; it++) {
            int row = w * 32 + it * 8 + r8;
            cp16(A + (size_t)(mb + row) * 1024 + kt + srcoff, As + (w * 32 + it * 8) * 64);
        }
        {
            int row = w * 16 + (r8 & 7);
            cp16(Wt + (size_t)(nb + w * 16 + r8) * 1024 + kt + srcoff, Bs + (w * 16) * 64);
            cp16(Wt + (size_t)(nb + w * 16 + 8 + r8) * 1024 + kt + srcoff, Bs + (w * 16 + 8) * 64);
            (void)row;
        }
        __syncthreads();
        #pragma unroll
        for (int kk = 0; kk < 64; kk += 32) {
            const int kg = (kk >> 3) + quad;
            const int pos = ((kg ^ cswz) * 8);
            bf16x8 af[4], bfr[2];
            #pragma unroll
            for (int i = 0; i < 4; i++)
                af[i] = *reinterpret_cast<const bf16x8*>(As + (wm + i * 16 + col) * 64 + pos);
            #pragma unroll
            for (int j = 0; j < 2; j++)
                bfr[j] = *reinterpret_cast<const bf16x8*>(Bs + (wn + j * 16 + col) * 64 + pos);
            #pragma unroll
            for (int i = 0; i < 4; i++)
                #pragma unroll
                for (int j = 0; j < 2; j++)
                    acc[i][j] = __builtin_amdgcn_mfma_f32_16x16x32_bf16(af[i], bfr[j], acc[i][j], 0, 0, 0);
        }
    }

    #pragma unroll
    for (int i = 0; i < 4; i++) {
        int mg = mb + wm + i * 16 + quad * 4;
        #pragma unroll
        for (int j = 0; j < 2; j++) {
            int ng = nb + wn + j * 16 + col;
            float bbv = b0[ng];
            #pragma unroll
            for (int r = 0; r < 4; r++)
                d0f[(size_t)(mg + r) * 1024 + ng] = acc[i][j][r] + bbv;
        }
    }
}

// ---------------------------------------------------------------- attention
// 1024 blocks: bh = bx&31, qt = 31-(bx>>5) (heavy tiles dispatched first).
// 4 waves x 16 q-rows. One softmax update per 64-key tile; row sums via
// ones-fragment MFMA (l = o[4]). Wave-uniform alpha-skip.
__global__ __launch_bounds__(256) void attn(
    const unsigned short* __restrict__ Q, const unsigned short* __restrict__ K,
    const unsigned short* __restrict__ Vt, unsigned short* __restrict__ O) {
    __shared__ __align__(16) unsigned short Ks[64 * 64];   // [key][dh] swizzled
    __shared__ __align__(16) unsigned short Vs[64 * 64];   // [dh][key] swizzled
    __shared__ __align__(16) unsigned short Ps[4][16 * 72]; // per-wave P [m][k]

    const int tid  = threadIdx.x;
    const int lane = tid & 63;
    const int w    = tid >> 6;
    const int col  = lane & 15;
    const int quad = lane >> 4;
    const int bh   = blockIdx.x & 31;
    const int qt   = 31 - (blockIdx.x >> 5);   // heavy first
    const int qb   = qt * 64;
    const int r8 = lane >> 3, gg = lane & 7;
    const int srcoff = ((gg ^ r8) * 8);
    const int cswz = col & 7;

    bf16x8 onesf;                               // B-frag: virtual V col of 1s
    #pragma unroll
    for (int j = 0; j < 8; j++) onesf[j] = (col == 0) ? (short)0x3F80 : (short)0;

    const int qrow = qb + w * 16 + col;
    const size_t qbase = ((size_t)bh * SS + qrow) * DHH;
    bf16x8 qlo = *reinterpret_cast<const bf16x8*>(Q + qbase + quad * 8);
    bf16x8 qhi = *reinterpret_cast<const bf16x8*>(Q + qbase + 32 + quad * 8);

    f32x4 o[5];
    #pragma unroll
    for (int d = 0; d < 5; d++) o[d] = (f32x4){0.f, 0.f, 0.f, 0.f};
    float m_i[4];
    #pragma unroll
    for (int r = 0; r < 4; r++) m_i[r] = -1e30f;

    for (int kt = 0; kt <= qt; kt++) {
        __syncthreads();
        #pragma unroll
        for (int it = 0; it < 2; it++) {     // stage K + V^T (8KB each)
            int row = w * 16 + it * 8 + r8;  // row&7 == r8
            cp16(K  + ((size_t)bh * SS + kt * 64 + row) * DHH + srcoff,
                 Ks + (w * 16 + it * 8) * 64);
            cp16(Vt + ((size_t)bh * DHH + row) * SS + kt * 64 + srcoff,
                 Vs + (w * 16 + it * 8) * 64);
        }
        __syncthreads();

        // ---- scores: 16 q-rows x 64 keys per wave
        f32x4 sc[4];
        #pragma unroll
        for (int nt = 0; nt < 4; nt++) {
            int key = nt * 16 + col;
            bf16x8 klo = *reinterpret_cast<const bf16x8*>(Ks + key * 64 + ((quad       ^ cswz) * 8));
            bf16x8 khi = *reinterpret_cast<const bf16x8*>(Ks + key * 64 + (((4 + quad) ^ cswz) * 8));
            f32x4 z = (f32x4){0.f, 0.f, 0.f, 0.f};
            z = __builtin_amdgcn_mfma_f32_16x16x32_bf16(qlo, klo, z, 0, 0, 0);
            z = __builtin_amdgcn_mfma_f32_16x16x32_bf16(qhi, khi, z, 0, 0, 0);
            sc[nt] = z;
        }
        if (kt == qt) {                      // causal mask, diagonal tile only
            #pragma unroll
            for (int nt = 0; nt < 4; nt++) {
                int kg = kt * 64 + nt * 16 + col;
                #pragma unroll
                for (int r = 0; r < 4; r++) {
                    int qg = qb + w * 16 + quad * 4 + r;
                    if (kg > qg) sc[nt][r] = -3.0e38f;
                }
            }
        }
        // ---- one online-softmax update per 64 keys
        float mnew[4];
        bool upd = false;
        #pragma unroll
        for (int r = 0; r < 4; r++) {
            float t = fmaxf(fmaxf(sc[0][r], sc[1][r]), fmaxf(sc[2][r], sc[3][r]));
            t = fmaxf(t, __shfl_xor(t, 1));
            t = fmaxf(t, __shfl_xor(t, 2));
            t = fmaxf(t, __shfl_xor(t, 4));
            t = fmaxf(t, __shfl_xor(t, 8));
            mnew[r] = fmaxf(m_i[r], t);
            upd = upd || (mnew[r] > m_i[r]);
        }
        if (__any(upd)) {                    // wave-uniform rescale skip
            #pragma unroll
            for (int r = 0; r < 4; r++) {
                float a = exp2f(m_i[r] - mnew[r]);
                #pragma unroll
                for (int d = 0; d < 5; d++) o[d][r] *= a;
            }
        }
        #pragma unroll
        for (int r = 0; r < 4; r++) m_i[r] = mnew[r];

        unsigned short* pw = Ps[w];          // C-layout -> A-layout
        #pragma unroll
        for (int nt = 0; nt < 4; nt++)
            #pragma unroll
            for (int r = 0; r < 4; r++)
                pw[(quad * 4 + r) * 72 + nt * 16 + col] = f2bf(exp2f(sc[nt][r] - mnew[r]));
        bf16x8 pf0 = *reinterpret_cast<const bf16x8*>(pw + col * 72 + quad * 8);
        bf16x8 pf1 = *reinterpret_cast<const bf16x8*>(pw + col * 72 + 32 + quad * 8);
        #pragma unroll
        for (int dt = 0; dt < 4; dt++) {
            int rv = dt * 16 + col;          // Vs row (= output d index)
            bf16x8 vf0 = *reinterpret_cast<const bf16x8*>(Vs + rv * 64 + ((quad       ^ cswz) * 8));
            bf16x8 vf1 = *reinterpret_cast<const bf16x8*>(Vs + rv * 64 + (((4 + quad) ^ cswz) * 8));
            o[dt] = __builtin_amdgcn_mfma_f32_16x16x32_bf16(pf0, vf0, o[dt], 0, 0, 0);
            o[dt] = __builtin_amdgcn_mfma_f32_16x16x32_bf16(pf1, vf1, o[dt], 0, 0, 0);
        }
        o[4] = __builtin_amdgcn_mfma_f32_16x16x32_bf16(pf0, onesf, o[4], 0, 0, 0);
        o[4] = __builtin_amdgcn_mfma_f32_16x16x32_bf16(pf1, onesf, o[4], 0, 0, 0);
    }

    // epilogue: l lives in o[4][r] of lanes col==0; broadcast within quad
    #pragma unroll
    for (int r = 0; r < 4; r++) {
        float lv = __shfl(o[4][r], lane & 48);
        float inv = 1.0f / lv;
        int sq = qb + w * 16 + quad * 4 + r;
        size_t base = ((size_t)(bh >> 4) * SS + sq) * DD + (size_t)(bh & 15) * DHH;
        #pragma unroll
        for (int dt = 0; dt < 4; dt++)
            O[base + dt * 16 + col] = f2bf(o[dt][r] * inv);
    }
}

// ---------------------------------------------------------------- launch
extern "C" void kernel_launch(void* const* d_in, const int* in_sizes, int n_in,
                              void* d_out, int out_size, void* d_ws, size_t ws_size,
                              hipStream_t stream) {
    (void)in_sizes; (void)n_in; (void)out_size; (void)ws_size;
    const float* x  = (const float*)d_in[0];
    const float* Wq = (const float*)d_in[2];
    const float* bq = (const float*)d_in[3];
    const float* Wk = (const float*)d_in[4];
    const float* bk = (const float*)d_in[5];
    const float* Wv = (const float*)d_in[6];
    const float* bv = (const float*)d_in[7];
    const float* Wo = (const float*)d_in[8];
    const float* bo = (const float*)d_in[9];
    float* out = (float*)d_out;

    // ws (40 MB): x_bf/O | Q | K | V^T | Wt x4
    char* ws = (char*)d_ws;
    unsigned short* xbf = (unsigned short*)(ws);
    unsigned short* qws = (unsigned short*)(ws + ((size_t)8  << 20));
    unsigned short* kws = (unsigned short*)(ws + ((size_t)16 << 20));
    unsigned short* vws = (unsigned short*)(ws + ((size_t)24 << 20));
    unsigned short* wt  = (unsigned short*)(ws + ((size_t)32 << 20));
    unsigned short* ows = xbf;   // O overwrites x_bf (dead after QKV GEMM)

    const int nx = BB * SS * DD;               // 4,194,304
    cvt_bf16<<<dim3(nx / 1024), 256, 0, stream>>>(x, xbf, nx);
    transpose_w<<<dim3(16, 16, 4), dim3(64, 4), 0, stream>>>(Wq, Wk, Wv, Wo, wt);
    gemm_qkv<<<dim3(24, 32), 256, 0, stream>>>(xbf, wt, bq, bk, bv,
                                               qws, kws, vws);
    attn<<<dim3(1024), 256, 0, stream>>>(qws, kws, vws, ows);
    gemm_out<<<dim3(16, 32), 256, 0, stream>>>(ows, wt + (size_t)3 * 1024 * 1024,
                                               bo, out);
}

// Round 6
// 212.477 us; speedup vs baseline: 1.2879x; 1.0458x over previous
//
#include <hip/hip_runtime.h>
#include <hip/hip_bf16.h>

// MultiHeadAttention: B=2, S=2048, D=1024, H=16, DH=64, causal, eval-mode.
// f32 I/O, bf16 MFMA internally.
// R6: attn processes 128-key double-tiles with ONE online-softmax update per
//     pair (halves shuffle/alpha/m VALU); truncating P->bf16 (bias cancels in
//     numerator/denominator); K/V double-buffered in LDS (41KB, 3 blocks/CU).

typedef short bf16x8 __attribute__((ext_vector_type(8)));
typedef float f32x4  __attribute__((ext_vector_type(4)));
typedef short s16x4  __attribute__((ext_vector_type(4)));

#define BB 2
#define SS 2048
#define DD 1024
#define HH 16
#define DHH 64

__device__ __forceinline__ unsigned short f2bf(float f) {
    unsigned u = __builtin_bit_cast(unsigned, f);
    u += 0x7FFFu + ((u >> 16) & 1u);      // RNE
    return (unsigned short)(u >> 16);
}
__device__ __forceinline__ unsigned short f2bf_trunc(float f) {
    return (unsigned short)(__builtin_bit_cast(unsigned, f) >> 16);
}
// async 16B global -> LDS (dest = wave-uniform base + lane*16B)
__device__ __forceinline__ void cp16(const unsigned short* g, unsigned short* l) {
    __builtin_amdgcn_global_load_lds(
        (const __attribute__((address_space(1))) unsigned int*)(g),
        (__attribute__((address_space(3))) unsigned int*)(l), 16, 0, 0);
}

// ---------------------------------------------------------------- f32 -> bf16
__global__ __launch_bounds__(256) void cvt_bf16(
    const float* __restrict__ src, unsigned short* __restrict__ dst, int n) {
    int i = (blockIdx.x * 256 + threadIdx.x) * 4;
    if (i >= n) return;
    float4 v = *reinterpret_cast<const float4*>(src + i);
    s16x4 p;
    p[0] = (short)f2bf(v.x); p[1] = (short)f2bf(v.y);
    p[2] = (short)f2bf(v.z); p[3] = (short)f2bf(v.w);
    *reinterpret_cast<s16x4*>(dst + i) = p;
}

// ---------------------------------------------------------------- transpose
__global__ __launch_bounds__(256) void transpose_w(
    const float* __restrict__ w0, const float* __restrict__ w1,
    const float* __restrict__ w2, const float* __restrict__ w3,
    unsigned short* __restrict__ dst) {
    __shared__ float tile[64][65];
    const float* src = blockIdx.z == 0 ? w0 : blockIdx.z == 1 ? w1
                     : blockIdx.z == 2 ? w2 : w3;
    unsigned short* out = dst + (size_t)blockIdx.z * (DD * DD);
    int bx = blockIdx.x * 64, by = blockIdx.y * 64;
    int tx = threadIdx.x, ty = threadIdx.y;          // block (64,4)
    #pragma unroll
    for (int i = 0; i < 64; i += 4)
        tile[ty + i][tx] = src[(size_t)(by + ty + i) * DD + bx + tx];
    __syncthreads();
    #pragma unroll
    for (int i = 0; i < 64; i += 4)
        out[(size_t)(bx + ty + i) * DD + by + tx] = f2bf(tile[tx][ty + i]);
}

// ---------------------------------------------------------------- QKV GEMM
// C[4096x3072] = A @ Wt^T (+bias). 128x128 tile, BK=64, 4 waves (2x2).
// LDS stride 64, k-groups XOR-swizzled by row&7; staging via cp16.
__global__ __launch_bounds__(256) void gemm_qkv(
    const unsigned short* __restrict__ A, const unsigned short* __restrict__ Wt,
    const float* __restrict__ b0, const float* __restrict__ b1,
    const float* __restrict__ b2,
    unsigned short* __restrict__ d0, unsigned short* __restrict__ d1,
    unsigned short* __restrict__ d2) {
    __shared__ __align__(16) unsigned short As[128 * 64];
    __shared__ __align__(16) unsigned short Bs[128 * 64];

    const int tid  = threadIdx.x;
    const int lane = tid & 63;
    const int w    = tid >> 6;
    const int col  = lane & 15;
    const int quad = lane >> 4;
    const int wm   = (w >> 1) * 64;
    const int wn   = (w & 1) * 64;
    const int mb   = blockIdx.y * 128;
    const int nb   = blockIdx.x * 128;

    const int r8 = lane >> 3, gg = lane & 7;
    const int srcoff = ((gg ^ r8) * 8);          // source k-group swizzle
    const int cswz = col & 7;                    // frag-read unswizzle key

    f32x4 acc[4][4];
    #pragma unroll
    for (int i = 0; i < 4; i++)
        #pragma unroll
        for (int j = 0; j < 4; j++) acc[i][j] = (f32x4){0.f, 0.f, 0.f, 0.f};

    for (int kt = 0; kt < 1024; kt += 64) {
        __syncthreads();
        #pragma unroll
        for (int it = 0; it < 4; it++) {
            int row = w * 32 + it * 8 + r8;      // row&7 == r8
            cp16(A  + (size_t)(mb + row) * 1024 + kt + srcoff, As + (w * 32 + it * 8) * 64);
            cp16(Wt + (size_t)(nb + row) * 1024 + kt + srcoff, Bs + (w * 32 + it * 8) * 64);
        }
        __syncthreads();
        #pragma unroll
        for (int kk = 0; kk < 64; kk += 32) {
            const int kg = (kk >> 3) + quad;
            const int pos = ((kg ^ cswz) * 8);
            bf16x8 af[4], bfr[4];
            #pragma unroll
            for (int i = 0; i < 4; i++)
                af[i] = *reinterpret_cast<const bf16x8*>(As + (wm + i * 16 + col) * 64 + pos);
            #pragma unroll
            for (int j = 0; j < 4; j++)
                bfr[j] = *reinterpret_cast<const bf16x8*>(Bs + (wn + j * 16 + col) * 64 + pos);
            #pragma unroll
            for (int i = 0; i < 4; i++)
                #pragma unroll
                for (int j = 0; j < 4; j++)
                    acc[i][j] = __builtin_amdgcn_mfma_f32_16x16x32_bf16(af[i], bfr[j], acc[i][j], 0, 0, 0);
        }
    }

    const float QSCALE = 0.125f * 1.44269504f;   // 1/sqrt(DH) * log2(e)
    #pragma unroll
    for (int i = 0; i < 4; i++) {
        int mg = mb + wm + i * 16 + quad * 4;    // C row = quad*4+reg
        #pragma unroll
        for (int j = 0; j < 4; j++) {
            int ng = nb + wn + j * 16 + col;     // C col = lane&15
            int sel = ng >> 10, n2 = ng & 1023;
            int h = n2 >> 6, dd2 = n2 & 63;
            int b = mg >> 11, s = mg & 2047;
            int bh = b * HH + h;
            const float* bp = sel == 0 ? b0 : sel == 1 ? b1 : b2;
            float bbv = bp[n2];
            if (sel == 0) {          // Q (pre-scaled for exp2 softmax)
                #pragma unroll
                for (int r = 0; r < 4; r++)
                    d0[((size_t)bh * SS + s + r) * DHH + dd2] = f2bf((acc[i][j][r] + bbv) * QSCALE);
            } else if (sel == 1) {   // K
                #pragma unroll
                for (int r = 0; r < 4; r++)
                    d1[((size_t)bh * SS + s + r) * DHH + dd2] = f2bf(acc[i][j][r] + bbv);
            } else {                 // V^T [b][h][d][s]
                s16x4 pack;
                #pragma unroll
                for (int r = 0; r < 4; r++) pack[r] = (short)f2bf(acc[i][j][r] + bbv);
                *reinterpret_cast<s16x4*>(d2 + ((size_t)bh * DHH + dd2) * SS + s) = pack;
            }
        }
    }
}

// ---------------------------------------------------------------- out GEMM
// C[4096x1024] = A @ Wt^T + b, f32 out. 128x64 tile, BK=64, 4 waves (2x2),
// wave tile 64x32 (acc 4x2). Grid (16,32)=512 blocks -> 2 blocks/CU.
__global__ __launch_bounds__(256) void gemm_out(
    const unsigned short* __restrict__ A, const unsigned short* __restrict__ Wt,
    const float* __restrict__ b0, float* __restrict__ d0f) {
    __shared__ __align__(16) unsigned short As[128 * 64];
    __shared__ __align__(16) unsigned short Bs[64 * 64];

    const int tid  = threadIdx.x;
    const int lane = tid & 63;
    const int w    = tid >> 6;
    const int col  = lane & 15;
    const int quad = lane >> 4;
    const int wm   = (w >> 1) * 64;
    const int wn   = (w & 1) * 32;
    const int mb   = blockIdx.y * 128;
    const int nb   = blockIdx.x * 64;

    const int r8 = lane >> 3, gg = lane & 7;
    const int srcoff = ((gg ^ r8) * 8);
    const int cswz = col & 7;

    f32x4 acc[4][2];
    #pragma unroll
    for (int i = 0; i < 4; i++)
        #pragma unroll
        for (int j = 0; j < 2; j++) acc[i][j] = (f32x4){0.f, 0.f, 0.f, 0.f};

    for (int kt = 0; kt < 1024; kt += 64) {
        __syncthreads();
        #pragma unroll
        for (int it = 0; it < 4; it++) {
            int row = w * 32 + it * 8 + r8;
            cp16(A + (size_t)(mb + row) * 1024 + kt + srcoff, As + (w * 32 + it * 8) * 64);
        }
        cp16(Wt + (size_t)(nb + w * 16 + r8) * 1024 + kt + srcoff, Bs + (w * 16) * 64);
        cp16(Wt + (size_t)(nb + w * 16 + 8 + r8) * 1024 + kt + srcoff, Bs + (w * 16 + 8) * 64);
        __syncthreads();
        #pragma unroll
        for (int kk = 0; kk < 64; kk += 32) {
            const int kg = (kk >> 3) + quad;
            const int pos = ((kg ^ cswz) * 8);
            bf16x8 af[4], bfr[2];
            #pragma unroll
            for (int i = 0; i < 4; i++)
                af[i] = *reinterpret_cast<const bf16x8*>(As + (wm + i * 16 + col) * 64 + pos);
            #pragma unroll
            for (int j = 0; j < 2; j++)
                bfr[j] = *reinterpret_cast<const bf16x8*>(Bs + (wn + j * 16 + col) * 64 + pos);
            #pragma unroll
            for (int i = 0; i < 4; i++)
                #pragma unroll
                for (int j = 0; j < 2; j++)
                    acc[i][j] = __builtin_amdgcn_mfma_f32_16x16x32_bf16(af[i], bfr[j], acc[i][j], 0, 0, 0);
        }
    }

    #pragma unroll
    for (int i = 0; i < 4; i++) {
        int mg = mb + wm + i * 16 + quad * 4;
        #pragma unroll
        for (int j = 0; j < 2; j++) {
            int ng = nb + wn + j * 16 + col;
            float bbv = b0[ng];
            #pragma unroll
            for (int r = 0; r < 4; r++)
                d0f[(size_t)(mg + r) * 1024 + ng] = acc[i][j][r] + bbv;
        }
    }
}

// ---------------------------------------------------------------- attention
// 1024 blocks: bh = bx&31, qt = 31-(bx>>5) (heavy first). 4 waves x 16 q-rows.
// 128-key double-tiles: one softmax update per pair. Row sums via
// ones-fragment MFMA (l = o[4]). Truncating P conversion (bias cancels).
__global__ __launch_bounds__(256, 3) void attn(
    const unsigned short* __restrict__ Q, const unsigned short* __restrict__ K,
    const unsigned short* __restrict__ Vt, unsigned short* __restrict__ O) {
    __shared__ __align__(16) unsigned short Ks[2][64 * 64];  // [key][dh] swizzled
    __shared__ __align__(16) unsigned short Vs[2][64 * 64];  // [dh][key] swizzled
    __shared__ __align__(16) unsigned short Ps[4][16 * 72];  // per-wave P [m][k]

    const int tid  = threadIdx.x;
    const int lane = tid & 63;
    const int w    = tid >> 6;
    const int col  = lane & 15;
    const int quad = lane >> 4;
    const int bh   = blockIdx.x & 31;
    const int qt   = 31 - (blockIdx.x >> 5);   // heavy first
    const int qb   = qt * 64;
    const int r8 = lane >> 3, gg = lane & 7;
    const int srcoff = ((gg ^ r8) * 8);
    const int cswz = col & 7;
    const int pos0 = (quad       ^ cswz) * 8;  // loop-invariant frag offsets
    const int pos1 = ((4 + quad) ^ cswz) * 8;

    bf16x8 onesf;                               // B-frag: virtual V col of 1s
    #pragma unroll
    for (int j = 0; j < 8; j++) onesf[j] = (col == 0) ? (short)0x3F80 : (short)0;

    const int qrow = qb + w * 16 + col;
    const size_t qbase = ((size_t)bh * SS + qrow) * DHH;
    bf16x8 qlo = *reinterpret_cast<const bf16x8*>(Q + qbase + quad * 8);
    bf16x8 qhi = *reinterpret_cast<const bf16x8*>(Q + qbase + 32 + quad * 8);

    f32x4 o[5];
    #pragma unroll
    for (int d = 0; d < 5; d++) o[d] = (f32x4){0.f, 0.f, 0.f, 0.f};
    float m_i[4];
    #pragma unroll
    for (int r = 0; r < 4; r++) m_i[r] = -1e30f;

    const int ntiles = qt + 1;
    for (int t0 = 0; t0 < ntiles; t0 += 2) {
        const bool two = (t0 + 1 < ntiles);
        __syncthreads();                       // WAR on Ks/Vs
        #pragma unroll
        for (int it = 0; it < 2; it++) {       // stage sub0: K + V^T (8KB each)
            int row = w * 16 + it * 8 + r8;    // row&7 == r8
            cp16(K  + ((size_t)bh * SS + t0 * 64 + row) * DHH + srcoff,
                 Ks[0] + (w * 16 + it * 8) * 64);
            cp16(Vt + ((size_t)bh * DHH + row) * SS + t0 * 64 + srcoff,
                 Vs[0] + (w * 16 + it * 8) * 64);
        }
        if (two) {
            #pragma unroll
            for (int it = 0; it < 2; it++) {   // stage sub1
                int row = w * 16 + it * 8 + r8;
                cp16(K  + ((size_t)bh * SS + (t0 + 1) * 64 + row) * DHH + srcoff,
                     Ks[1] + (w * 16 + it * 8) * 64);
                cp16(Vt + ((size_t)bh * DHH + row) * SS + (t0 + 1) * 64 + srcoff,
                     Vs[1] + (w * 16 + it * 8) * 64);
            }
        }
        __syncthreads();

        // ---- scores: 16 q-rows x (64 or 128) keys per wave
        f32x4 sc[8];
        #pragma unroll
        for (int nt = 0; nt < 4; nt++) {
            int key = nt * 16 + col;
            bf16x8 klo = *reinterpret_cast<const bf16x8*>(Ks[0] + key * 64 + pos0);
            bf16x8 khi = *reinterpret_cast<const bf16x8*>(Ks[0] + key * 64 + pos1);
            f32x4 z = (f32x4){0.f, 0.f, 0.f, 0.f};
            z = __builtin_amdgcn_mfma_f32_16x16x32_bf16(qlo, klo, z, 0, 0, 0);
            z = __builtin_amdgcn_mfma_f32_16x16x32_bf16(qhi, khi, z, 0, 0, 0);
            sc[nt] = z;
        }
        if (two) {
            #pragma unroll
            for (int nt = 0; nt < 4; nt++) {
                int key = nt * 16 + col;
                bf16x8 klo = *reinterpret_cast<const bf16x8*>(Ks[1] + key * 64 + pos0);
                bf16x8 khi = *reinterpret_cast<const bf16x8*>(Ks[1] + key * 64 + pos1);
                f32x4 z = (f32x4){0.f, 0.f, 0.f, 0.f};
                z = __builtin_amdgcn_mfma_f32_16x16x32_bf16(qlo, klo, z, 0, 0, 0);
                z = __builtin_amdgcn_mfma_f32_16x16x32_bf16(qhi, khi, z, 0, 0, 0);
                sc[4 + nt] = z;
            }
        }
        // causal mask (diagonal tile only; t0==qt implies !two)
        if (t0 == qt || (two && t0 + 1 == qt)) {
            const int sb = (t0 == qt) ? 0 : 4;
            const int tb = (t0 == qt) ? t0 : t0 + 1;
            #pragma unroll
            for (int nt = 0; nt < 4; nt++) {
                int kg = tb * 64 + nt * 16 + col;
                #pragma unroll
                for (int r = 0; r < 4; r++) {
                    int qg = qb + w * 16 + quad * 4 + r;
                    if (kg > qg) sc[sb + nt][r] = -3.0e38f;
                }
            }
        }
        // ---- ONE online-softmax update per 128 keys
        float mnew[4];
        bool upd = false;
        #pragma unroll
        for (int r = 0; r < 4; r++) {
            float t = fmaxf(fmaxf(sc[0][r], sc[1][r]), fmaxf(sc[2][r], sc[3][r]));
            if (two)
                t = fmaxf(t, fmaxf(fmaxf(sc[4][r], sc[5][r]), fmaxf(sc[6][r], sc[7][r])));
            t = fmaxf(t, __shfl_xor(t, 1));
            t = fmaxf(t, __shfl_xor(t, 2));
            t = fmaxf(t, __shfl_xor(t, 4));
            t = fmaxf(t, __shfl_xor(t, 8));
            mnew[r] = fmaxf(m_i[r], t);
            upd = upd || (mnew[r] > m_i[r]);
        }
        if (__any(upd)) {                      // wave-uniform rescale skip
            #pragma unroll
            for (int r = 0; r < 4; r++) {
                float a = exp2f(m_i[r] - mnew[r]);
                #pragma unroll
                for (int d = 0; d < 5; d++) o[d][r] *= a;
            }
        }
        #pragma unroll
        for (int r = 0; r < 4; r++) m_i[r] = mnew[r];

        unsigned short* pw = Ps[w];
        // ---- sub0: P (C-layout -> A-layout via per-wave LDS) + PV
        #pragma unroll
        for (int nt = 0; nt < 4; nt++)
            #pragma unroll
            for (int r = 0; r < 4; r++)
                pw[(quad * 4 + r) * 72 + nt * 16 + col] = f2bf_trunc(exp2f(sc[nt][r] - mnew[r]));
        {
            bf16x8 pf0 = *reinterpret_cast<const bf16x8*>(pw + col * 72 + quad * 8);
            bf16x8 pf1 = *reinterpret_cast<const bf16x8*>(pw + col * 72 + 32 + quad * 8);
            #pragma unroll
            for (int dt = 0; dt < 4; dt++) {
                int rv = dt * 16 + col;
                bf16x8 vf0 = *reinterpret_cast<const bf16x8*>(Vs[0] + rv * 64 + pos0);
                bf16x8 vf1 = *reinterpret_cast<const bf16x8*>(Vs[0] + rv * 64 + pos1);
                o[dt] = __builtin_amdgcn_mfma_f32_16x16x32_bf16(pf0, vf0, o[dt], 0, 0, 0);
                o[dt] = __builtin_amdgcn_mfma_f32_16x16x32_bf16(pf1, vf1, o[dt], 0, 0, 0);
            }
            o[4] = __builtin_amdgcn_mfma_f32_16x16x32_bf16(pf0, onesf, o[4], 0, 0, 0);
            o[4] = __builtin_amdgcn_mfma_f32_16x16x32_bf16(pf1, onesf, o[4], 0, 0, 0);
        }
        // ---- sub1 (same-wave DS ordering makes Ps reuse sync-free)
        if (two) {
            #pragma unroll
            for (int nt = 0; nt < 4; nt++)
                #pragma unroll
                for (int r = 0; r < 4; r++)
                    pw[(quad * 4 + r) * 72 + nt * 16 + col] = f2bf_trunc(exp2f(sc[4 + nt][r] - mnew[r]));
            bf16x8 pf0 = *reinterpret_cast<const bf16x8*>(pw + col * 72 + quad * 8);
            bf16x8 pf1 = *reinterpret_cast<const bf16x8*>(pw + col * 72 + 32 + quad * 8);
            #pragma unroll
            for (int dt = 0; dt < 4; dt++) {
                int rv = dt * 16 + col;
                bf16x8 vf0 = *reinterpret_cast<const bf16x8*>(Vs[1] + rv * 64 + pos0);
                bf16x8 vf1 = *reinterpret_cast<const bf16x8*>(Vs[1] + rv * 64 + pos1);
                o[dt] = __builtin_amdgcn_mfma_f32_16x16x32_bf16(pf0, vf0, o[dt], 0, 0, 0);
                o[dt] = __builtin_amdgcn_mfma_f32_16x16x32_bf16(pf1, vf1, o[dt], 0, 0, 0);
            }
            o[4] = __builtin_amdgcn_mfma_f32_16x16x32_bf16(pf0, onesf, o[4], 0, 0, 0);
            o[4] = __builtin_amdgcn_mfma_f32_16x16x32_bf16(pf1, onesf, o[4], 0, 0, 0);
        }
    }

    // epilogue: l lives in o[4][r] of lanes col==0; broadcast within quad
    #pragma unroll
    for (int r = 0; r < 4; r++) {
        float lv = __shfl(o[4][r], lane & 48);
        float inv = 1.0f / lv;
        int sq = qb + w * 16 + quad * 4 + r;
        size_t base = ((size_t)(bh >> 4) * SS + sq) * DD + (size_t)(bh & 15) * DHH;
        #pragma unroll
        for (int dt = 0; dt < 4; dt++)
            O[base + dt * 16 + col] = f2bf(o[dt][r] * inv);
    }
}

// ---------------------------------------------------------------- launch
extern "C" void kernel_launch(void* const* d_in, const int* in_sizes, int n_in,
                              void* d_out, int out_size, void* d_ws, size_t ws_size,
                              hipStream_t stream) {
    (void)in_sizes; (void)n_in; (void)out_size; (void)ws_size;
    const float* x  = (const float*)d_in[0];
    const float* Wq = (const float*)d_in[2];
    const float* bq = (const float*)d_in[3];
    const float* Wk = (const float*)d_in[4];
    const float* bk = (const float*)d_in[5];
    const float* Wv = (const float*)d_in[6];
    const float* bv = (const float*)d_in[7];
    const float* Wo = (const float*)d_in[8];
    const float* bo = (const float*)d_in[9];
    float* out = (float*)d_out;

    // ws (40 MB): x_bf/O | Q | K | V^T | Wt x4
    char* ws = (char*)d_ws;
    unsigned short* xbf = (unsigned short*)(ws);
    unsigned short* qws = (unsigned short*)(ws + ((size_t)8  << 20));
    unsigned short* kws = (unsigned short*)(ws + ((size_t)16 << 20));
    unsigned short* vws = (unsigned short*)(ws + ((size_t)24 << 20));
    unsigned short* wt  = (unsigned short*)(ws + ((size_t)32 << 20));
    unsigned short* ows = xbf;   // O overwrites x_bf (dead after QKV GEMM)

    const int nx = BB * SS * DD;               // 4,194,304
    cvt_bf16<<<dim3(nx / 1024), 256, 0, stream>>>(x, xbf, nx);
    transpose_w<<<dim3(16, 16, 4), dim3(64, 4), 0, stream>>>(Wq, Wk, Wv, Wo, wt);
    gemm_qkv<<<dim3(24, 32), 256, 0, stream>>>(xbf, wt, bq, bk, bv,
                                               qws, kws, vws);
    attn<<<dim3(1024), 256, 0, stream>>>(qws, kws, vws, ows);
    gemm_out<<<dim3(16, 32), 256, 0, stream>>>(ows, wt + (size_t)3 * 1024 * 1024,
                                               bo, out);
}